// Round 6
// baseline (249.648 us; speedup 1.0000x reference)
//
#include <hip/hip_runtime.h>

#define CC 384
#define HW 3136            // 56*56
#define WIDTH 56
#define PLANE_ELEMS (CC*HW)  // 1204224
#define EPS 1e-5f

// bf16 x_pw for plane p lives in the 2nd half of plane p's f32 output slot:
// ushort index = p*6272 + 3136 + j   (slot = 12544 B = 6272 ushorts)
#define SLOT_U 6272
#define HALF_U 3136

// ---------------- fast-path workspace layout (ushort units) ----------------
// wf  : W in fragment order  [12 kt][24 og][64 lane][8]      = 147456 u
// btg : Toeplitz B per chan  [384 c][13 ky][16 n][32 k]      = 2555904 u
// xf  : x A-fragments        [16 b][49 jt][12 kt][4 jf][64 lane][8]
#define WF_U (12*24*64*8)          // 147456
#define BT_U 6656
#define BT_TOTAL (CC*BT_U)         // 2555904
#define XF_U (16*49*12*4*64*8)     // 19267584
#define WS_FAST_BYTES ((size_t)(WF_U + BT_TOTAL + XF_U) * 2)   // 43,941,888 B

// prep kernel block partition
#define NSTAGE (12*49*16)          // 9408 stage_xfrag blocks
#define NPREP  (NSTAGE + CC + 72)  // + pack_bt(384) + pack_wf(72)

// ---------------- old-path (fallback) W layout ----------------
#define WROW 40
#define WSTEP_U (CC*WROW)        // 15360 ushorts per k-step
#define WP_TOTAL (12*WSTEP_U)    // 184320 ushorts

typedef __attribute__((ext_vector_type(8))) short bf16x8;
typedef __attribute__((ext_vector_type(4))) float f32x4;

static __device__ __forceinline__ float bf2f(unsigned short u) {
  union { unsigned int i; float f; } x; x.i = ((unsigned int)u) << 16; return x.f;
}
static __device__ __forceinline__ unsigned short f2bf(float f) {
  union { float f; unsigned int i; } x; x.f = f;
  unsigned int r = x.i + 0x7fffu + ((x.i >> 16) & 1u);
  return (unsigned short)(r >> 16);
}

// Branch-free exact-form GELU: erf via Abramowitz-Stegun 7.1.26
// (|eps_erf| <= 1.5e-7 -> invisible vs bf16-path noise).
static __device__ __forceinline__ float gelu_fast(float v) {
  float x  = v * 0.70710678118654752f;
  float ax = fabsf(x);
  float t  = __builtin_amdgcn_rcpf(fmaf(0.3275911f, ax, 1.0f));
  float p  = fmaf(1.061405429f, t, -1.453152027f);
  p = fmaf(p, t, 1.421413741f);
  p = fmaf(p, t, -0.284496736f);
  p = fmaf(p, t, 0.254829592f);
  p = p * t;
  float e  = __expf(-ax * ax);
  float ea = fmaf(-p, e, 1.0f);          // erf(|x|)
  float er = copysignf(ea, x);
  return 0.5f * v * (1.0f + er);
}

// ---------------------------------------------------------------------------
// prep: merged pack_wf + pack_bt + stage_xfrag (one launch, independent work).
// Blocks [0, NSTAGE): stage_xfrag; [NSTAGE, NSTAGE+CC): pack_bt; rest: pack_wf.
// ---------------------------------------------------------------------------
__global__ __launch_bounds__(256) void prep(
    const float* __restrict__ xin,
    const float* __restrict__ wmat,
    const float* __restrict__ dwkw,
    unsigned short* __restrict__ wf,
    unsigned short* __restrict__ btg,
    unsigned short* __restrict__ xf)
{
  __shared__ __align__(16) unsigned short Xt[64 * 40];   // [j][k], pad 40
  const int bid = blockIdx.x;
  const int tid = threadIdx.x;

  if (bid < NSTAGE) {
    // ---- stage_xfrag: f32 x -> bf16 A-fragments, one (kt,jt,b) per block ----
    const int kt = bid % 12;
    const int r  = bid / 12;
    const int jt = r % 49;
    const int b  = r / 49;
    const int lane = tid & 63, wid = tid >> 6;
    const int l15 = lane & 15, q = lane >> 4;

    const float* src = xin + (size_t)b * PLANE_ELEMS
                     + (size_t)(kt * 32 + wid * 8) * HW + jt * 64 + lane;
    bf16x8 u;
    #pragma unroll
    for (int i = 0; i < 8; ++i) u[i] = (short)f2bf(src[(size_t)i * HW]);
    *((bf16x8*)&Xt[lane * 40 + wid * 8]) = u;
    __syncthreads();
    bf16x8 f = *((const bf16x8*)&Xt[(wid * 16 + l15) * 40 + q * 8]);  // jf = wid
    *((bf16x8*)(xf + ((size_t)((b * 49 + jt) * 12 + kt) * 4 + wid) * 512
                   + lane * 8)) = f;
  } else if (bid < NSTAGE + CC) {
    // ---- pack_bt: Bt[c][ky][n][k] = w[c][ky][k-n-2] ----
    const int c = bid - NSTAGE;
    for (int i = tid; i < BT_U; i += 256) {
      int ky = i >> 9, rem = i & 511, n = rem >> 5, k = rem & 31;
      int kx = k - n - 2;
      unsigned short v = 0;
      if ((unsigned)kx < 13u) v = f2bf(dwkw[c * 169 + ky * 13 + kx]);
      btg[(size_t)c * BT_U + i] = v;
    }
  } else {
    // ---- pack_wf: W f32 -> bf16 in MFMA B-fragment order ----
    int t = (bid - NSTAGE - CC) * 256 + tid;
    int kt  = t / (24 * 64);
    int rem = t - kt * 24 * 64;
    int og  = rem >> 6;
    int lane = rem & 63;
    int o  = og * 16 + (lane & 15);
    int k0 = kt * 32 + (lane >> 4) * 8;
    bf16x8 u;
    #pragma unroll
    for (int i = 0; i < 8; ++i) u[i] = (short)f2bf(wmat[o * CC + k0 + i]);
    *((bf16x8*)(wf + (size_t)t * 8)) = u;
  }
}

// ---------------------------------------------------------------------------
// pw_gemm_frag: barrier-free, LDS-free GEMM + BN + residual -> bf16 stash.
// ---------------------------------------------------------------------------
__global__ __launch_bounds__(256, 3) void pw_gemm_frag(
    const float* __restrict__ xin,
    const unsigned short* __restrict__ wf,
    const unsigned short* __restrict__ xf,
    const float* __restrict__ pwg, const float* __restrict__ pwb,
    const float* __restrict__ pwm, const float* __restrict__ pwv,
    unsigned short* __restrict__ xpw)   // = (ushort*)d_out
{
  const int tid = threadIdx.x;
  const int jt = blockIdx.x, oh = blockIdx.y, b = blockIdx.z;
  const int j0 = jt * 64;
  const int lane = tid & 63, wid = tid >> 6;
  const int l15 = lane & 15, q = lane >> 4;
  const size_t bbase = (size_t)b * PLANE_ELEMS;

  f32x4 acc[4][3] = {};

  const unsigned short* xbase = xf + (size_t)(b * 49 + jt) * (12 * 2048) + lane * 8;
  const unsigned short* wbase = wf + lane * 8;
  const int ogb = oh * 12 + wid * 3;

  #pragma unroll 2
  for (int kt = 0; kt < 12; ++kt) {
    bf16x8 a[4];
    #pragma unroll
    for (int jf = 0; jf < 4; ++jf)
      a[jf] = *((const bf16x8*)(xbase + (kt * 4 + jf) * 512));
    #pragma unroll
    for (int of = 0; of < 3; ++of) {
      bf16x8 w = *((const bf16x8*)(wbase + (kt * 24 + ogb + of) * 512));
      #pragma unroll
      for (int jf = 0; jf < 4; ++jf)
        acc[jf][of] = __builtin_amdgcn_mfma_f32_16x16x32_bf16(a[jf], w, acc[jf][of], 0, 0, 0);
    }
  }

  // ---- epilogue: BN + residual, write bf16 stash ----
  const int o0 = oh * 192 + wid * 48;
  #pragma unroll
  for (int of = 0; of < 3; ++of) {
    const int o = o0 + of * 16 + l15;
    const float s = pwg[o] * rsqrtf(pwv[o] + EPS);
    const float t = pwb[o] - pwm[o] * s;
    #pragma unroll
    for (int jf = 0; jf < 4; ++jf) {
      const int j = j0 + jf * 16 + q * 4;
      f32x4 av = acc[jf][of];
      float4 xr = *((const float4*)(xin + bbase + (size_t)o * HW + j));
      ushort4 w4;
      w4.x = f2bf(av[0] * s + t + xr.x);
      w4.y = f2bf(av[1] * s + t + xr.y);
      w4.z = f2bf(av[2] * s + t + xr.z);
      w4.w = f2bf(av[3] * s + t + xr.w);
      size_t pidx = (size_t)(b * CC + o) * SLOT_U + HALF_U + j;
      *((ushort4*)(xpw + pidx)) = w4;
    }
  }
}

// ---------------------------------------------------------------------------
// Fallback path (ws too small): round-2 v2 kernels, verbatim.
// ---------------------------------------------------------------------------
__global__ __launch_bounds__(256) void pack_w_old(
    const float* __restrict__ wmat, unsigned short* __restrict__ wp)
{
  int i = blockIdx.x * 256 + threadIdx.x;
  int kt  = i / WSTEP_U;
  int rem = i - kt * WSTEP_U;
  int o   = rem / WROW;
  int kk  = rem - o * WROW;
  unsigned short v = 0;
  if (kk < 32) v = f2bf(wmat[o * CC + kt * 32 + kk]);
  wp[i] = v;
}

__global__ __launch_bounds__(256) void pack_bt_old(
    const float* __restrict__ dwkw, unsigned short* __restrict__ btg)
{
  const int c = blockIdx.x;
  for (int i = threadIdx.x; i < BT_U; i += 256) {
    int ky = i >> 9, rem = i & 511, n = rem >> 5, k = rem & 31;
    int kx = k - n - 2;
    unsigned short v = 0;
    if ((unsigned)kx < 13u) v = f2bf(dwkw[c * 169 + ky * 13 + kx]);
    btg[(size_t)c * BT_U + i] = v;
  }
}

__global__ __launch_bounds__(256, 3) void pw_gemm_bn_res_old(
    const float* __restrict__ xin,
    const unsigned short* __restrict__ wp,
    const float* __restrict__ pwg, const float* __restrict__ pwb,
    const float* __restrict__ pwm, const float* __restrict__ pwv,
    unsigned short* __restrict__ xpw)
{
  __shared__ __align__(16) unsigned short Xt[64 * 40];
  __shared__ __align__(16) unsigned short Wt[WSTEP_U];
  __shared__ float scaleS[CC];
  __shared__ float shiftS[CC];

  const int tid = threadIdx.x;
  const int j0 = blockIdx.x * 64;
  const int b  = blockIdx.y;
  const size_t bbase = (size_t)b * PLANE_ELEMS;

  for (int o = tid; o < CC; o += 256) {
    float s = pwg[o] * rsqrtf(pwv[o] + EPS);
    scaleS[o] = s;
    shiftS[o] = pwb[o] - pwm[o] * s;
  }

  const int lane = tid & 63;
  const int wid  = tid >> 6;
  const int l15  = lane & 15;
  const int q    = lane >> 4;

  f32x4 acc[4][6] = {};
  const float* xsrc0 = xin + bbase + (size_t)(wid * 8) * HW + (j0 + lane);

  for (int kt = 0; kt < 12; ++kt) {
    const int c0 = kt * 32;
    __syncthreads();
    {
      const float* src = xsrc0 + (size_t)c0 * HW;
      float v0 = src[0 * HW], v1 = src[1 * HW], v2 = src[2 * HW], v3 = src[3 * HW];
      float v4 = src[4 * HW], v5 = src[5 * HW], v6 = src[6 * HW], v7 = src[7 * HW];
      bf16x8 u;
      u[0] = (short)f2bf(v0); u[1] = (short)f2bf(v1);
      u[2] = (short)f2bf(v2); u[3] = (short)f2bf(v3);
      u[4] = (short)f2bf(v4); u[5] = (short)f2bf(v5);
      u[6] = (short)f2bf(v6); u[7] = (short)f2bf(v7);
      *((bf16x8*)&Xt[lane * 40 + wid * 8]) = u;
    }
    {
      const unsigned short* g = wp + (size_t)kt * WSTEP_U;
      #pragma unroll
      for (int i = 0; i < 8; ++i) {
        int c = i * 4 + wid;
        if (c < 30) {
          __builtin_amdgcn_global_load_lds(
              (const __attribute__((address_space(1))) unsigned int*)(g + c * 512 + lane * 8),
              (__attribute__((address_space(3))) unsigned int*)(&Wt[c * 512]),
              16, 0, 0);
        }
      }
    }
    __syncthreads();

    bf16x8 a[4];
    #pragma unroll
    for (int jf = 0; jf < 4; ++jf)
      a[jf] = *((const bf16x8*)&Xt[(jf * 16 + l15) * 40 + q * 8]);

    #pragma unroll
    for (int of = 0; of < 6; ++of) {
      bf16x8 bb = *((const bf16x8*)&Wt[(wid * 96 + of * 16 + l15) * WROW + q * 8]);
      #pragma unroll
      for (int jf = 0; jf < 4; ++jf)
        acc[jf][of] = __builtin_amdgcn_mfma_f32_16x16x32_bf16(a[jf], bb, acc[jf][of], 0, 0, 0);
    }
  }

  const int ob = wid * 96;
  #pragma unroll
  for (int of = 0; of < 6; ++of) {
    const int o = ob + of * 16 + l15;
    const float s = scaleS[o], t = shiftS[o];
    #pragma unroll
    for (int jf = 0; jf < 4; ++jf) {
      const int j = j0 + jf * 16 + q * 4;
      f32x4 av = acc[jf][of];
      float4 xr = *((const float4*)(xin + bbase + (size_t)o * HW + j));
      ushort4 w4;
      w4.x = f2bf(av[0] * s + t + xr.x);
      w4.y = f2bf(av[1] * s + t + xr.y);
      w4.z = f2bf(av[2] * s + t + xr.z);
      w4.w = f2bf(av[3] * s + t + xr.w);
      size_t pidx = (size_t)(b * CC + o) * SLOT_U + HALF_U + j;
      *((ushort4*)(xpw + pidx)) = w4;
    }
  }
}

// ---------------------------------------------------------------------------
// Kernel B v3 (MFMA Toeplitz): 13x13 depthwise conv + BN_k + center-tap
// branch + GELU, one block per (b,c) plane.
// Round-5 change (LDS-pipe-bound): VGPR=40 revealed bfr was NOT hoisted —
// compiler re-read Bt from LDS per tile (52 b128/thread), and the Bt pattern
// (row stride 64B = 16 dw) is an 8-way bank conflict => the 6.39M
// SQ_LDS_BANK_CONFLICT. Fix: drop the Bt LDS buffer entirely; load the 13
// B-fragments straight from global btg (contiguous 1KB/wave, L2-resident)
// into registers before the loop. __launch_bounds__(256,4) keeps them
// resident (~100 VGPR, same 4-waves/SIMD tier). LDS-pipe traffic halves,
// conflicts vanish, LDS 27.1KB -> 13.4KB.
// ---------------------------------------------------------------------------
#define TSTRIDE 88
#define TROWS 76
#define NCH 11   // b128 chunks per tile row (88 u16 = 11 * 8)

__global__ __launch_bounds__(256, 4) void dw_conv_mfma(
    float* __restrict__ outf,
    const unsigned short* __restrict__ stash,
    const unsigned short* __restrict__ btg,   // pre-packed Bt (or nullptr)
    const float* __restrict__ dwkw,
    const float* __restrict__ dkg, const float* __restrict__ dkb,
    const float* __restrict__ dkm, const float* __restrict__ dkv,
    const float* __restrict__ d1w,
    const float* __restrict__ d1g, const float* __restrict__ d1b,
    const float* __restrict__ d1m, const float* __restrict__ d1v)
{
  __shared__ __align__(16) unsigned short tile[TROWS * TSTRIDE];  // 13376 B

  const int bc = blockIdx.x;
  const int c = bc % CC;
  const size_t plane_u = (size_t)bc * SLOT_U + HALF_U;
  const size_t plane_f = (size_t)bc * HW;
  const int tid = threadIdx.x;
  const int lane = tid & 63;
  const int wid  = tid >> 6;
  const int l15  = lane & 15;
  const int q    = lane >> 4;

  // ---- B fragments: straight from global (coalesced, L2-resident) ----
  bf16x8 bfr[13];
  if (btg) {
    const unsigned short* g = btg + (size_t)c * BT_U + l15 * 32 + q * 8;
    #pragma unroll
    for (int ky = 0; ky < 13; ++ky)
      bfr[ky] = *((const bf16x8*)(g + ky * 512));
  } else {
    #pragma unroll
    for (int ky = 0; ky < 13; ++ky) {
      bf16x8 u;
      #pragma unroll
      for (int i = 0; i < 8; ++i) {
        int kx = q * 8 + i - l15 - 2;
        u[i] = (short)(((unsigned)kx < 13u) ? f2bf(dwkw[c * 169 + ky * 13 + kx])
                                            : (unsigned short)0);
      }
      bfr[ky] = u;
    }
  }

  // ---- stage plane into zero-padded bf16 tile: all-vector b128 writes ----
  for (int i = tid; i < TROWS * NCH; i += 256) {
    int r = i / NCH, ch = i - r * NCH;
    int gy = r - 6;
    bf16x8 v = {0,0,0,0,0,0,0,0};
    if ((unsigned)gy < (unsigned)WIDTH && ch >= 1 && ch <= 7)
      v = *((const bf16x8*)(stash + plane_u + gy * WIDTH + (ch - 1) * 8));
    *((bf16x8*)&tile[r * TSTRIDE + ch * 8]) = v;
  }

  const float sk = dkg[c] * rsqrtf(dkv[c] + EPS);
  const float tk = dkb[c] - dkm[c] * sk;
  const float s1 = d1g[c] * rsqrtf(d1v[c] + EPS);
  const float a1 = d1w[c] * s1;
  const float t1 = d1b[c] - d1m[c] * s1;
  const float tsum = tk + t1;

  __syncthreads();

  // 16 output tiles of 16x16 cover 64x64 >= 56x56; 4 waves -> 4 tiles each
  for (int t = wid; t < 16; t += 4) {
    const int y0 = (t >> 2) * 16, x0 = (t & 3) * 16;
    f32x4 acc = {0.f, 0.f, 0.f, 0.f};
    #pragma unroll
    for (int ky = 0; ky < 13; ++ky) {
      bf16x8 a = *((const bf16x8*)&tile[(y0 + l15 + ky) * TSTRIDE + x0 + q * 8]);
      acc = __builtin_amdgcn_mfma_f32_16x16x32_bf16(a, bfr[ky], acc, 0, 0, 0);
    }
    const int x = x0 + l15;
    if (x < WIDTH) {
      #pragma unroll
      for (int r = 0; r < 4; ++r) {
        const int y = y0 + q * 4 + r;
        if (y < WIDTH) {
          float ctr = bf2f(tile[(y + 6) * TSTRIDE + x + 8]);
          float v = acc[r] * sk + tsum + ctr * a1;
          outf[plane_f + y * WIDTH + x] = gelu_fast(v);
        }
      }
    }
  }
}

extern "C" void kernel_launch(void* const* d_in, const int* in_sizes, int n_in,
                              void* d_out, int out_size, void* d_ws, size_t ws_size,
                              hipStream_t stream) {
  const float* x     = (const float*)d_in[0];
  const float* pw_w  = (const float*)d_in[1];
  const float* pw_g  = (const float*)d_in[2];
  const float* pw_b  = (const float*)d_in[3];
  const float* pw_m  = (const float*)d_in[4];
  const float* pw_v  = (const float*)d_in[5];
  const float* dwk_w = (const float*)d_in[6];
  const float* dwk_g = (const float*)d_in[7];
  const float* dwk_b = (const float*)d_in[8];
  const float* dwk_m = (const float*)d_in[9];
  const float* dwk_v = (const float*)d_in[10];
  const float* dw1_w = (const float*)d_in[11];
  const float* dw1_g = (const float*)d_in[12];
  const float* dw1_b = (const float*)d_in[13];
  const float* dw1_m = (const float*)d_in[14];
  const float* dw1_v = (const float*)d_in[15];
  float* outf = (float*)d_out;
  unsigned short* outu = (unsigned short*)d_out;
  unsigned short* ws = (unsigned short*)d_ws;

  unsigned short* btg = nullptr;

  if (ws_size >= WS_FAST_BYTES) {
    // ---- fast path: fragment-order GEMM, no barriers ----
    unsigned short* wf = ws;
    btg               = ws + WF_U;
    unsigned short* xf = ws + WF_U + BT_TOTAL;

    prep<<<NPREP, 256, 0, stream>>>(x, pw_w, dwk_w, wf, btg, xf);

    dim3 gridA(49, 2, 16);
    pw_gemm_frag<<<gridA, 256, 0, stream>>>(x, wf, xf, pw_g, pw_b, pw_m, pw_v, outu);
  } else {
    // ---- fallback: round-2 v2 path ----
    unsigned short* wpack = ws;
    pack_w_old<<<WP_TOTAL / 256, 256, 0, stream>>>(pw_w, wpack);
    if (ws_size >= (size_t)(WP_TOTAL + BT_TOTAL) * sizeof(unsigned short)) {
      btg = wpack + WP_TOTAL;
      pack_bt_old<<<CC, 256, 0, stream>>>(dwk_w, btg);
    }
    dim3 gridA(HW / 64, 16);
    pw_gemm_bn_res_old<<<gridA, 256, 0, stream>>>(x, wpack, pw_g, pw_b, pw_m, pw_v, outu);
  }

  dim3 gridB(16 * CC);
  dw_conv_mfma<<<gridB, 256, 0, stream>>>(outf, outu, btg, dwk_w,
      dwk_g, dwk_b, dwk_m, dwk_v, dw1_w, dw1_g, dw1_b, dw1_m, dw1_v);
}